// Round 5
// baseline (938.114 us; speedup 1.0000x reference)
//
#include <hip/hip_runtime.h>
#include <hip/hip_bf16.h>
#include <stdint.h>
#include <type_traits>

// Problem constants: B=256, T=512, D=300, H=128, 4H=512, C=6
#define NB 256
#define NT 512
#define ND 300
#define NH 128
#define NG 512
#define NC 6

typedef __attribute__((ext_vector_type(8))) short short8;
typedef __attribute__((ext_vector_type(4))) float f32x4;

static __device__ __forceinline__ float bf2f(unsigned int u) {
  return __builtin_bit_cast(float, (u & 0xffffu) << 16);
}
static __device__ __forceinline__ unsigned short f2bf(float f) {
  return __builtin_bit_cast(unsigned short, __float2bfloat16(f));
}
static __device__ __forceinline__ unsigned int packbf(float a, float b) {
  return (unsigned int)f2bf(a) | ((unsigned int)f2bf(b) << 16);
}
static __device__ __forceinline__ float ld1(const unsigned short* p) { return bf2f(*p); }
static __device__ __forceinline__ float ld1(const float* p) { return *p; }
static __device__ __forceinline__ void st1(unsigned short* p, float v) { *p = f2bf(v); }
static __device__ __forceinline__ void st1(float* p, float v) { *p = v; }

static __device__ __forceinline__ float sigmoid_fast(float x) {
  return __builtin_amdgcn_rcpf(1.f + __expf(-x));
}
static __device__ __forceinline__ float tanh_fast(float x) {
  return 1.f - 2.f * __builtin_amdgcn_rcpf(__expf(2.f * x) + 1.f);
}

// ---- staging loads: 4 K-elems -> 2 packed bf16 pairs ------------------------
static __device__ __forceinline__ uint2 load4bf_fast(const unsigned short* row, int k) {
  return *(const uint2*)(row + k);  // 8B-aligned (k%4==0)
}
static __device__ __forceinline__ uint2 load4bf_fast(const float* row, int k) {
  float4 f = *(const float4*)(row + k);
  uint2 v;
  v.x = packbf(f.x, f.y);
  v.y = packbf(f.z, f.w);
  return v;
}
static __device__ __forceinline__ uint2 load4bf(const unsigned short* row, int k, int lim) {
  if (k + 3 < lim) return load4bf_fast(row, k);
  unsigned int e0 = (k + 0 < lim) ? row[k + 0] : 0;
  unsigned int e1 = (k + 1 < lim) ? row[k + 1] : 0;
  unsigned int e2 = (k + 2 < lim) ? row[k + 2] : 0;
  unsigned int e3 = (k + 3 < lim) ? row[k + 3] : 0;
  uint2 v;
  v.x = e0 | (e1 << 16);
  v.y = e2 | (e3 << 16);
  return v;
}
static __device__ __forceinline__ uint2 load4bf(const float* row, int k, int lim) {
  if (k + 3 < lim) return load4bf_fast(row, k);
  float f0 = (k + 0 < lim) ? row[k + 0] : 0.f;
  float f1 = (k + 1 < lim) ? row[k + 1] : 0.f;
  float f2 = (k + 2 < lim) ? row[k + 2] : 0.f;
  float f3 = (k + 3 < lim) ? row[k + 3] : 0.f;
  uint2 v;
  v.x = packbf(f0, f1);
  v.y = packbf(f2, f3);
  return v;
}

// gx loads: 4 consecutive values -> f32x4
static __device__ __forceinline__ f32x4 ldgx4(const unsigned short* p) {
  uint2 v = *(const uint2*)p;
  f32x4 r;
  r[0] = bf2f(v.x);
  r[1] = bf2f(v.x >> 16);
  r[2] = bf2f(v.y);
  r[3] = bf2f(v.y >> 16);
  return r;
}
static __device__ __forceinline__ f32x4 ldgx4(const float* p) {
  return *(const f32x4*)p;
}

// ---------------------------------------------------------------------------
// Dtype detector (flag: 0 = bf16 inputs, 1 = fp32 inputs).
// ---------------------------------------------------------------------------
__global__ void detect_dtype(const unsigned short* __restrict__ X, int* __restrict__ flag) {
  __shared__ int cnt;
  if (threadIdx.x == 0) cnt = 0;
  __syncthreads();
  int c = 0;
  for (int i = threadIdx.x; i < 512; i += 64) {
    unsigned int u = X[i];
    unsigned int e = (u >> 7) & 0xffu;
    if (u == 0u || (e >= 97u && e <= 157u)) c++;
  }
  atomicAdd(&cnt, c);
  __syncthreads();
  if (threadIdx.x == 0) *flag = (cnt >= 448) ? 0 : 1;
}

// ---------------------------------------------------------------------------
// Phase 1: gx[m][n] = sum_k x[b,t,k] * W_ih[n][k].
// 128Mx64N tile, 4 waves (2x2), MFMA 16x16x32. Register double-buffered
// staging: chunk k+1 loads issue right after the barrier and retire during
// MFMA. K-loop fully unrolled: chunks 0..8 branch-free, chunk 9 masked.
// ---------------------------------------------------------------------------
template <typename XT, typename GXT>
__global__ __launch_bounds__(256) void gx_gemm(const int* __restrict__ flag, int want,
                                               const XT* __restrict__ X,
                                               const XT* __restrict__ Wih,
                                               const int* __restrict__ lengths,
                                               GXT* __restrict__ gx,
                                               int b_base, int t_base, int Tc) {
  if (*flag != want) return;
  const int mb = blockIdx.x;
  const int m0 = mb << 7;
  const int bc = m0 / Tc;
  const int trel0 = m0 % Tc;
  const int b = b_base + bc;
  const int t0 = t_base + trel0;
  const int len = lengths[b];
  if (t0 >= len) return;

  __shared__ unsigned short As[128][40];
  __shared__ unsigned short Bs[64][40];

  const int tid = threadIdx.x;
  const int lane = tid & 63;
  const int wave = tid >> 6;
  const int wm = wave & 1;
  const int wn = wave >> 1;
  const int lq = lane >> 4;
  const int lr = lane & 15;

  const int rA = tid >> 1, cA = (tid & 1) * 16;
  const int rB = tid >> 2, cB = (tid & 3) * 8;
  const XT* xrow = X + ((size_t)b * NT + t0 + rA) * ND;

  for (int nt = 0; nt < 8; ++nt) {
    const int n0 = nt << 6;
    const XT* wrow = Wih + (size_t)(n0 + rB) * ND;

    f32x4 acc[4][2];
#pragma unroll
    for (int i = 0; i < 4; ++i)
#pragma unroll
      for (int j = 0; j < 2; ++j) {
        f32x4 z = {0.f, 0.f, 0.f, 0.f};
        acc[i][j] = z;
      }

    uint2 av[4], bv[2];
#pragma unroll
    for (int g4 = 0; g4 < 4; ++g4) av[g4] = load4bf_fast(xrow, cA + g4 * 4);
#pragma unroll
    for (int g4 = 0; g4 < 2; ++g4) bv[g4] = load4bf_fast(wrow, cB + g4 * 4);

#pragma unroll
    for (int kc9 = 0; kc9 < 10; ++kc9) {
      __syncthreads();
#pragma unroll
      for (int g4 = 0; g4 < 4; ++g4) *(uint2*)&As[rA][cA + g4 * 4] = av[g4];
#pragma unroll
      for (int g4 = 0; g4 < 2; ++g4) *(uint2*)&Bs[rB][cB + g4 * 4] = bv[g4];
      __syncthreads();

      if (kc9 < 9) {  // preload next chunk; retires during MFMA below
        const int kn = (kc9 + 1) * 32;
        if (kc9 < 8) {  // compile-time: chunks 1..8 fully in-bounds
#pragma unroll
          for (int g4 = 0; g4 < 4; ++g4) av[g4] = load4bf_fast(xrow, kn + cA + g4 * 4);
#pragma unroll
          for (int g4 = 0; g4 < 2; ++g4) bv[g4] = load4bf_fast(wrow, kn + cB + g4 * 4);
        } else {  // chunk 9: 288..319 masked at 300
#pragma unroll
          for (int g4 = 0; g4 < 4; ++g4) av[g4] = load4bf(xrow, kn + cA + g4 * 4, ND);
#pragma unroll
          for (int g4 = 0; g4 < 2; ++g4) bv[g4] = load4bf(wrow, kn + cB + g4 * 4, ND);
        }
      }

      short8 af[4], bq[2];
#pragma unroll
      for (int tm = 0; tm < 4; ++tm)
        af[tm] = *(const short8*)&As[wm * 64 + tm * 16 + lr][lq * 8];
#pragma unroll
      for (int tn = 0; tn < 2; ++tn)
        bq[tn] = *(const short8*)&Bs[wn * 32 + tn * 16 + lr][lq * 8];
#pragma unroll
      for (int tm = 0; tm < 4; ++tm)
#pragma unroll
        for (int tn = 0; tn < 2; ++tn)
          acc[tm][tn] =
              __builtin_amdgcn_mfma_f32_16x16x32_bf16(af[tm], bq[tn], acc[tm][tn], 0, 0, 0);
    }

    // C/D layout: col = lane&15, row = (lane>>4)*4 + reg
#pragma unroll
    for (int tm = 0; tm < 4; ++tm)
#pragma unroll
      for (int tn = 0; tn < 2; ++tn)
#pragma unroll
        for (int rg = 0; rg < 4; ++rg) {
          const int tileRow = wm * 64 + tm * 16 + lq * 4 + rg;
          if (t0 + tileRow < len) {
            const int col = n0 + wn * 32 + tn * 16 + lr;
            st1(gx + (size_t)(m0 + tileRow) * NG + col, acc[tm][tn][rg]);
          }
        }
  }
}

// ---------------------------------------------------------------------------
// Phase 2: per-batch recurrence via MFMA matvec. 8 waves; wave w owns units
// [16w,16w+16). A = W_hh fragments (4 gates x 4 k-chunks, 64 VGPRs).
// B = h broadcast to all 16 columns: 4 ds_read_b128/wave/step.
// D-layout gives each lane all 4 gates of its 4 units IN REGISTERS ->
// no shuffles, no gate LDS round-trip, ONE barrier/step.
// ---------------------------------------------------------------------------
template <typename XT, typename GXT>
__global__ __launch_bounds__(512, 2) void lstm_rec(const int* __restrict__ flag, int want,
                                                   const GXT* __restrict__ gx,
                                                   const XT* __restrict__ Whh,
                                                   const XT* __restrict__ bih,
                                                   const XT* __restrict__ bhh,
                                                   const XT* __restrict__ fcw,
                                                   const XT* __restrict__ fcb,
                                                   const int* __restrict__ lengths,
                                                   XT* __restrict__ out,
                                                   float* __restrict__ hstate,
                                                   float* __restrict__ cstate,
                                                   int b_base, int t_base, int Tc) {
  if (*flag != want) return;
  const int bc = blockIdx.x;
  const int b = b_base + bc;
  int len = lengths[b];
  if (len > NT) len = NT;
  if (len < 0) len = 0;
  const bool first = (t_base == 0);
  const bool last = (t_base + Tc >= NT);
  const int tend = (len < t_base + Tc) ? len : (t_base + Tc);
  if (!last && tend <= t_base) return;  // no steps; ws state untouched
  int nsteps = tend - t_base;
  if (nsteps < 0) nsteps = 0;

  const int tid = threadIdx.x;
  const int w8 = tid >> 6;   // wave: units [w8*16, w8*16+16)
  const int l = tid & 63;
  const int q = l >> 4;      // quad group
  const int m = l & 15;      // A-frag row select / column id
  const int u0 = w8 * 16 + q * 4;  // first unit of this lane's D rows

  __shared__ __align__(16) unsigned short hpk[2][NH];  // packed bf16 h, dbuf
  __shared__ __align__(16) float hf[NH];               // final h (FC epilogue)

  // A fragments: afr[g][c] = W_hh[g*128 + w8*16 + m][c*32 + q*8 .. +8]
  short8 afr[4][4];
#pragma unroll
  for (int g = 0; g < 4; ++g) {
    const int row = g * NH + w8 * 16 + m;
    if constexpr (std::is_same_v<XT, unsigned short>) {
#pragma unroll
      for (int c = 0; c < 4; ++c)
        afr[g][c] = *(const short8*)(Whh + (size_t)row * NH + c * 32 + q * 8);
    } else {
#pragma unroll
      for (int c = 0; c < 4; ++c) {
        const float* p = Whh + (size_t)row * NH + c * 32 + q * 8;
        float4 f0 = *(const float4*)p;
        float4 f1 = *(const float4*)(p + 4);
        union { unsigned int u[4]; short8 s; } cv;
        cv.u[0] = packbf(f0.x, f0.y);
        cv.u[1] = packbf(f0.z, f0.w);
        cv.u[2] = packbf(f1.x, f1.y);
        cv.u[3] = packbf(f1.z, f1.w);
        afr[g][c] = cv.s;
      }
    }
  }

  // bias per (gate, reg)
  f32x4 biasv[4];
#pragma unroll
  for (int g = 0; g < 4; ++g)
#pragma unroll
    for (int r = 0; r < 4; ++r)
      biasv[g][r] = ld1(bih + g * NH + u0 + r) + ld1(bhh + g * NH + u0 + r);

  f32x4 cv, hv;
  if (!first) {
    hv = *(const f32x4*)&hstate[(size_t)bc * NH + u0];
    cv = *(const f32x4*)&cstate[(size_t)bc * NH + u0];
  } else {
    f32x4 z = {0.f, 0.f, 0.f, 0.f};
    hv = z;
    cv = z;
  }
  if (m == 0) {
    uint2 hp;
    hp.x = packbf(hv[0], hv[1]);
    hp.y = packbf(hv[2], hv[3]);
    *(uint2*)&hpk[0][u0] = hp;  // ds_write_b64
  }
  __syncthreads();

  const GXT* gxc = gx + (size_t)bc * Tc * NG;
  f32x4 gc[4], gn[4];
  {
    f32x4 z = {0.f, 0.f, 0.f, 0.f};
#pragma unroll
    for (int g = 0; g < 4; ++g) {
      gc[g] = (0 < nsteps) ? ldgx4(gxc + g * NH + u0) : z;
      gn[g] = (1 < nsteps) ? ldgx4(gxc + NG + g * NH + u0) : z;
    }
  }

  for (int s = 0; s < nsteps; ++s) {
    f32x4 gf[4];
    {
      f32x4 z = {0.f, 0.f, 0.f, 0.f};
#pragma unroll
      for (int g = 0; g < 4; ++g)
        gf[g] = (s + 2 < nsteps) ? ldgx4(gxc + (size_t)(s + 2) * NG + g * NH + u0) : z;
    }

    // B fragments: h[k] broadcast to all columns; k = c*32 + q*8 + j
    short8 bfr[4];
    const unsigned short* hrow = hpk[s & 1];
#pragma unroll
    for (int c = 0; c < 4; ++c) bfr[c] = *(const short8*)&hrow[c * 32 + q * 8];

    f32x4 acc[4];
#pragma unroll
    for (int g = 0; g < 4; ++g) {
      f32x4 z = {0.f, 0.f, 0.f, 0.f};
      acc[g] = z;
#pragma unroll
      for (int c = 0; c < 4; ++c)
        acc[g] = __builtin_amdgcn_mfma_f32_16x16x32_bf16(afr[g][c], bfr[c], acc[g], 0, 0, 0);
    }

    // update 4 units, all gates in-lane (i,f,g,o = gates 0..3)
#pragma unroll
    for (int r = 0; r < 4; ++r) {
      const float pi = acc[0][r] + biasv[0][r] + gc[0][r];
      const float pf = acc[1][r] + biasv[1][r] + gc[1][r];
      const float pg = acc[2][r] + biasv[2][r] + gc[2][r];
      const float po = acc[3][r] + biasv[3][r] + gc[3][r];
      const float ig = sigmoid_fast(pi);
      const float fg = sigmoid_fast(pf);
      const float gg = tanh_fast(pg);
      const float og = sigmoid_fast(po);
      cv[r] = fmaf(fg, cv[r], ig * gg);
      hv[r] = og * tanh_fast(cv[r]);
    }
    if (m == 0) {
      uint2 hp;
      hp.x = packbf(hv[0], hv[1]);
      hp.y = packbf(hv[2], hv[3]);
      *(uint2*)&hpk[(s + 1) & 1][u0] = hp;
    }
    __syncthreads();

#pragma unroll
    for (int g = 0; g < 4; ++g) {
      gc[g] = gn[g];
      gn[g] = gf[g];
    }
  }

  if (!last) {
    if (m == 0) {
      *(f32x4*)&hstate[(size_t)bc * NH + u0] = hv;
      *(f32x4*)&cstate[(size_t)bc * NH + u0] = cv;
    }
  } else {
    if (m == 0) *(f32x4*)&hf[u0] = hv;
    __syncthreads();
    if (tid < NC) {
      float acc = ld1(fcb + tid);
      const XT* wv = fcw + (size_t)tid * NH;
#pragma unroll
      for (int k = 0; k < NH; ++k) acc = fmaf(ld1(wv + k), hf[k], acc);
      st1(out + (size_t)b * NC + tid, acc);
    }
  }
}

// ---------------------------------------------------------------------------
template <typename XT, typename GXT>
static void run_variant(int want, const int* flag, void* const* d_in, XT* out,
                        GXT* gx, float* hstate, float* cstate, int NBc, int Tc,
                        hipStream_t stream) {
  const XT* X = (const XT*)d_in[0];
  const XT* Wih = (const XT*)d_in[1];
  const XT* Whh = (const XT*)d_in[2];
  const XT* bih = (const XT*)d_in[3];
  const XT* bhh = (const XT*)d_in[4];
  const XT* fcw = (const XT*)d_in[5];
  const XT* fcb = (const XT*)d_in[6];
  const int* lengths = (const int*)d_in[7];
  for (int bb = 0; bb < NB; bb += NBc) {
    for (int tb = 0; tb < NT; tb += Tc) {
      gx_gemm<XT, GXT><<<dim3((NBc * Tc) / 128), dim3(256), 0, stream>>>(
          flag, want, X, Wih, lengths, gx, bb, tb, Tc);
      lstm_rec<XT, GXT><<<dim3(NBc), dim3(512), 0, stream>>>(
          flag, want, gx, Whh, bih, bhh, fcw, fcb, lengths, out, hstate, cstate, bb, tb, Tc);
    }
  }
}

extern "C" void kernel_launch(void* const* d_in, const int* in_sizes, int n_in,
                              void* d_out, int out_size, void* d_ws, size_t ws_size,
                              hipStream_t stream) {
  int* flag = (int*)d_ws;
  detect_dtype<<<dim3(1), dim3(64), 0, stream>>>((const unsigned short*)d_in[0], flag);

  const size_t full_f32 = (size_t)NB * NT * NG * sizeof(float);
  const size_t full_bf16 = (size_t)NB * NT * NG * 2;
  const size_t base = 512;

  int NBc, Tc;
  char* gx_raw;
  float* hstate = (float*)((char*)d_ws + base);
  bool gx_is_f32;

  if (ws_size >= base + full_f32) {
    NBc = NB; Tc = NT; gx_is_f32 = true;
    gx_raw = (char*)d_ws + base;
  } else if (ws_size >= base + full_bf16) {
    NBc = NB; Tc = NT; gx_is_f32 = false;
    gx_raw = (char*)d_ws + base;
  } else {
    Tc = 128; gx_is_f32 = false;
    NBc = 1;
    for (int cand : {64, 16, 4}) {
      size_t need = base + (size_t)cand * NH * 2 * sizeof(float) + (size_t)cand * Tc * NG * 2;
      if (ws_size >= need) { NBc = cand; break; }
    }
    gx_raw = (char*)d_ws + base + (size_t)NBc * NH * 2 * sizeof(float);
  }
  float* cstate = hstate + (size_t)NBc * NH;

  if (gx_is_f32) {
    run_variant<unsigned short, float>(0, flag, d_in, (unsigned short*)d_out,
                                       (float*)gx_raw, hstate, cstate, NBc, Tc, stream);
    run_variant<float, float>(1, flag, d_in, (float*)d_out, (float*)gx_raw, hstate,
                              cstate, NBc, Tc, stream);
  } else {
    run_variant<unsigned short, unsigned short>(0, flag, d_in, (unsigned short*)d_out,
                                                (unsigned short*)gx_raw, hstate, cstate,
                                                NBc, Tc, stream);
    run_variant<float, unsigned short>(1, flag, d_in, (float*)d_out,
                                       (unsigned short*)gx_raw, hstate, cstate, NBc, Tc,
                                       stream);
  }
}

// Round 6
// 637.642 us; speedup vs baseline: 1.4712x; 1.4712x over previous
//
#include <hip/hip_runtime.h>
#include <hip/hip_bf16.h>
#include <stdint.h>
#include <type_traits>

// Problem constants: B=256, T=512, D=300, H=128, 4H=512, C=6
#define NB 256
#define NT 512
#define ND 300
#define NH 128
#define NG 512
#define NC 6

typedef __attribute__((ext_vector_type(8))) short short8;
typedef __attribute__((ext_vector_type(4))) float f32x4;

static __device__ __forceinline__ float bf2f(unsigned int u) {
  return __builtin_bit_cast(float, (u & 0xffffu) << 16);
}
static __device__ __forceinline__ unsigned short f2bf(float f) {
  return __builtin_bit_cast(unsigned short, __float2bfloat16(f));
}
static __device__ __forceinline__ unsigned int packbf(float a, float b) {
  return (unsigned int)f2bf(a) | ((unsigned int)f2bf(b) << 16);
}
static __device__ __forceinline__ float ld1(const unsigned short* p) { return bf2f(*p); }
static __device__ __forceinline__ float ld1(const float* p) { return *p; }
static __device__ __forceinline__ void st1(unsigned short* p, float v) { *p = f2bf(v); }
static __device__ __forceinline__ void st1(float* p, float v) { *p = v; }

static __device__ __forceinline__ float sigmoid_fast(float x) {
  return __builtin_amdgcn_rcpf(1.f + __expf(-x));
}
static __device__ __forceinline__ float tanh_fast(float x) {
  return 1.f - 2.f * __builtin_amdgcn_rcpf(__expf(2.f * x) + 1.f);
}

// ---- staging loads: 4 K-elems -> 2 packed bf16 pairs ------------------------
static __device__ __forceinline__ uint2 load4bf_fast(const unsigned short* row, int k) {
  return *(const uint2*)(row + k);  // 8B-aligned (k%4==0)
}
static __device__ __forceinline__ uint2 load4bf_fast(const float* row, int k) {
  float4 f = *(const float4*)(row + k);
  uint2 v;
  v.x = packbf(f.x, f.y);
  v.y = packbf(f.z, f.w);
  return v;
}
static __device__ __forceinline__ uint2 load4bf(const unsigned short* row, int k, int lim) {
  if (k + 3 < lim) return load4bf_fast(row, k);
  unsigned int e0 = (k + 0 < lim) ? row[k + 0] : 0;
  unsigned int e1 = (k + 1 < lim) ? row[k + 1] : 0;
  unsigned int e2 = (k + 2 < lim) ? row[k + 2] : 0;
  unsigned int e3 = (k + 3 < lim) ? row[k + 3] : 0;
  uint2 v;
  v.x = e0 | (e1 << 16);
  v.y = e2 | (e3 << 16);
  return v;
}
static __device__ __forceinline__ uint2 load4bf(const float* row, int k, int lim) {
  if (k + 3 < lim) return load4bf_fast(row, k);
  float f0 = (k + 0 < lim) ? row[k + 0] : 0.f;
  float f1 = (k + 1 < lim) ? row[k + 1] : 0.f;
  float f2 = (k + 2 < lim) ? row[k + 2] : 0.f;
  float f3 = (k + 3 < lim) ? row[k + 3] : 0.f;
  uint2 v;
  v.x = packbf(f0, f1);
  v.y = packbf(f2, f3);
  return v;
}

// ---------------------------------------------------------------------------
// Dtype detector (flag: 0 = bf16 inputs, 1 = fp32 inputs).
// ---------------------------------------------------------------------------
__global__ void detect_dtype(const unsigned short* __restrict__ X, int* __restrict__ flag) {
  __shared__ int cnt;
  if (threadIdx.x == 0) cnt = 0;
  __syncthreads();
  int c = 0;
  for (int i = threadIdx.x; i < 512; i += 64) {
    unsigned int u = X[i];
    unsigned int e = (u >> 7) & 0xffu;
    if (u == 0u || (e >= 97u && e <= 157u)) c++;
  }
  atomicAdd(&cnt, c);
  __syncthreads();
  if (threadIdx.x == 0) *flag = (cnt >= 448) ? 0 : 1;
}

// ---------------------------------------------------------------------------
// Phase 1: gx[m][n] = sum_k x[b,t,k] * W_ih[n][k]  + (bih[n]+bhh[n]).
// 128Mx64N tile, 4 waves (2x2), MFMA 16x16x32. Distance-2 register prefetch:
// chunk k+2's loads are issued at chunk k, giving ~2 chunk-bodies of latency
// slack before the vmcnt drain at chunk k+2's LDS store.
// ---------------------------------------------------------------------------
template <typename XT, typename GXT>
__global__ __launch_bounds__(256) void gx_gemm(const int* __restrict__ flag, int want,
                                               const XT* __restrict__ X,
                                               const XT* __restrict__ Wih,
                                               const XT* __restrict__ bih,
                                               const XT* __restrict__ bhh,
                                               const int* __restrict__ lengths,
                                               GXT* __restrict__ gx,
                                               int b_base, int t_base, int Tc) {
  if (*flag != want) return;
  const int mb = blockIdx.x;
  const int m0 = mb << 7;
  const int bc = m0 / Tc;
  const int trel0 = m0 % Tc;
  const int b = b_base + bc;
  const int t0 = t_base + trel0;
  const int len = lengths[b];
  if (t0 >= len) return;

  __shared__ unsigned short As[128][40];
  __shared__ unsigned short Bs[64][40];

  const int tid = threadIdx.x;
  const int lane = tid & 63;
  const int wave = tid >> 6;
  const int wm = wave & 1;
  const int wn = wave >> 1;
  const int lq = lane >> 4;
  const int lr = lane & 15;

  const int rA = tid >> 1, cA = (tid & 1) * 16;
  const int rB = tid >> 2, cB = (tid & 3) * 8;
  const XT* xrow = X + ((size_t)b * NT + t0 + rA) * ND;

  for (int nt = 0; nt < 8; ++nt) {
    const int n0 = nt << 6;
    const XT* wrow = Wih + (size_t)(n0 + rB) * ND;

    f32x4 acc[4][2];
#pragma unroll
    for (int i = 0; i < 4; ++i)
#pragma unroll
      for (int j = 0; j < 2; ++j) {
        f32x4 z = {0.f, 0.f, 0.f, 0.f};
        acc[i][j] = z;
      }

    // two in-flight chunk buffers (distance-2 prefetch)
    uint2 av[2][4], bv[2][2];
#pragma unroll
    for (int g4 = 0; g4 < 4; ++g4) {
      av[0][g4] = load4bf_fast(xrow, cA + g4 * 4);
      av[1][g4] = load4bf_fast(xrow, 32 + cA + g4 * 4);
    }
#pragma unroll
    for (int g4 = 0; g4 < 2; ++g4) {
      bv[0][g4] = load4bf_fast(wrow, cB + g4 * 4);
      bv[1][g4] = load4bf_fast(wrow, 32 + cB + g4 * 4);
    }

#pragma unroll
    for (int kc9 = 0; kc9 < 10; ++kc9) {
      const int bi = kc9 & 1;
      __syncthreads();
#pragma unroll
      for (int g4 = 0; g4 < 4; ++g4) *(uint2*)&As[rA][cA + g4 * 4] = av[bi][g4];
#pragma unroll
      for (int g4 = 0; g4 < 2; ++g4) *(uint2*)&Bs[rB][cB + g4 * 4] = bv[bi][g4];
      __syncthreads();

      if (kc9 < 8) {  // preload chunk kc9+2 into the buffer just consumed
        const int kn = (kc9 + 2) * 32;
        if (kc9 < 7) {  // chunks 2..8 fully in-bounds (compile-time)
#pragma unroll
          for (int g4 = 0; g4 < 4; ++g4) av[bi][g4] = load4bf_fast(xrow, kn + cA + g4 * 4);
#pragma unroll
          for (int g4 = 0; g4 < 2; ++g4) bv[bi][g4] = load4bf_fast(wrow, kn + cB + g4 * 4);
        } else {  // chunk 9: 288..319 masked at 300
#pragma unroll
          for (int g4 = 0; g4 < 4; ++g4) av[bi][g4] = load4bf(xrow, kn + cA + g4 * 4, ND);
#pragma unroll
          for (int g4 = 0; g4 < 2; ++g4) bv[bi][g4] = load4bf(wrow, kn + cB + g4 * 4, ND);
        }
      }

      short8 af[4], bq[2];
#pragma unroll
      for (int tm = 0; tm < 4; ++tm)
        af[tm] = *(const short8*)&As[wm * 64 + tm * 16 + lr][lq * 8];
#pragma unroll
      for (int tn = 0; tn < 2; ++tn)
        bq[tn] = *(const short8*)&Bs[wn * 32 + tn * 16 + lr][lq * 8];
#pragma unroll
      for (int tm = 0; tm < 4; ++tm)
#pragma unroll
        for (int tn = 0; tn < 2; ++tn)
          acc[tm][tn] =
              __builtin_amdgcn_mfma_f32_16x16x32_bf16(af[tm], bq[tn], acc[tm][tn], 0, 0, 0);
    }

    // Epilogue: add bias (bih+bhh) per output column, store.
    // C/D layout: col = lane&15, row = (lane>>4)*4 + reg
    float bias_c[2];
#pragma unroll
    for (int tn = 0; tn < 2; ++tn) {
      const int col = n0 + wn * 32 + tn * 16 + lr;
      bias_c[tn] = ld1(bih + col) + ld1(bhh + col);
    }
#pragma unroll
    for (int tm = 0; tm < 4; ++tm)
#pragma unroll
      for (int tn = 0; tn < 2; ++tn)
#pragma unroll
        for (int rg = 0; rg < 4; ++rg) {
          const int tileRow = wm * 64 + tm * 16 + lq * 4 + rg;
          if (t0 + tileRow < len) {
            const int col = n0 + wn * 32 + tn * 16 + lr;
            st1(gx + (size_t)(m0 + tileRow) * NG + col, acc[tm][tn][rg] + bias_c[tn]);
          }
        }
  }
}

// ---------------------------------------------------------------------------
// Phase 2: per-batch recurrence via MFMA matvec. 8 waves; wave w owns units
// [16w,16w+16). A = W_hh fragments (4 gates x 4 k-chunks, 64 VGPRs).
// B = h broadcast to all 16 columns: 4 ds_read_b128/wave/step.
// Update: lane (q,m) handles ONLY unit u0+(m&3) (4x lane redundancy, no extra
// instructions): 4 gx loads + 12 cndmask acc-selects + 10 trans/lane/step.
// Bias pre-folded into gx. ONE barrier/step. waves_per_eu pinned to 2 so the
// 256-VGPR budget holds afr without spills (round-5 failure mode).
// ---------------------------------------------------------------------------
template <typename XT, typename GXT>
__global__ __launch_bounds__(512)
__attribute__((amdgpu_waves_per_eu(2, 2)))
void lstm_rec(const int* __restrict__ flag, int want,
              const GXT* __restrict__ gx,
              const XT* __restrict__ Whh,
              const XT* __restrict__ fcw,
              const XT* __restrict__ fcb,
              const int* __restrict__ lengths,
              XT* __restrict__ out,
              float* __restrict__ hstate,
              float* __restrict__ cstate,
              int b_base, int t_base, int Tc) {
  if (*flag != want) return;
  const int bc = blockIdx.x;
  const int b = b_base + bc;
  int len = lengths[b];
  if (len > NT) len = NT;
  if (len < 0) len = 0;
  const bool first = (t_base == 0);
  const bool last = (t_base + Tc >= NT);
  const int tend = (len < t_base + Tc) ? len : (t_base + Tc);
  if (!last && tend <= t_base) return;  // no steps; ws state untouched
  int nsteps = tend - t_base;
  if (nsteps < 0) nsteps = 0;

  const int tid = threadIdx.x;
  const int w8 = tid >> 6;         // wave: units [w8*16, w8*16+16)
  const int l = tid & 63;
  const int q = l >> 4;            // quad group
  const int m = l & 15;            // A-frag row select / D column id
  const int u0 = w8 * 16 + q * 4;  // first unit of this lane's D rows
  const int r = m & 3;             // unit handled by this lane
  const int u = u0 + r;

  __shared__ __align__(16) unsigned short hpk[2][NH];  // packed bf16 h, dbuf
  __shared__ __align__(16) float hf[NH];               // final h (FC epilogue)

  // A fragments: afr[g][c] = W_hh[g*128 + w8*16 + m][c*32 + q*8 .. +8]
  short8 afr[4][4];
#pragma unroll
  for (int g = 0; g < 4; ++g) {
    const int row = g * NH + w8 * 16 + m;
    if constexpr (std::is_same_v<XT, unsigned short>) {
#pragma unroll
      for (int c = 0; c < 4; ++c)
        afr[g][c] = *(const short8*)(Whh + (size_t)row * NH + c * 32 + q * 8);
    } else {
#pragma unroll
      for (int c = 0; c < 4; ++c) {
        const float* p = Whh + (size_t)row * NH + c * 32 + q * 8;
        float4 f0 = *(const float4*)p;
        float4 f1 = *(const float4*)(p + 4);
        union { unsigned int uu[4]; short8 s; } cv2;
        cv2.uu[0] = packbf(f0.x, f0.y);
        cv2.uu[1] = packbf(f0.z, f0.w);
        cv2.uu[2] = packbf(f1.x, f1.y);
        cv2.uu[3] = packbf(f1.z, f1.w);
        afr[g][c] = cv2.s;
      }
    }
  }

  float hcur = 0.f, ccur = 0.f;
  if (!first) {
    hcur = hstate[(size_t)bc * NH + u];
    ccur = cstate[(size_t)bc * NH + u];
  }
  if (m < 4) hpk[0][u] = f2bf(hcur);
  __syncthreads();

  // gx pointers for this lane's unit: 4 gates at offsets g*128
  const GXT* gp = gx + (size_t)bc * Tc * NG + u;
  const int lastidx = (nsteps > 0) ? nsteps - 1 : 0;
  float g_c[4], g_n[4];
#pragma unroll
  for (int g = 0; g < 4; ++g) {
    g_c[g] = ld1(gp + g * NH);                                 // idx 0
    g_n[g] = ld1(gp + (size_t)((1 < lastidx) ? 1 : lastidx) * NG + g * NH);  // idx min(1,last)
  }

  for (int s = 0; s < nsteps; ++s) {
    // prefetch step s+2 (clamped; clamped loads are valid, never consumed)
    int idx = s + 2;
    if (idx > lastidx) idx = lastidx;
    float g_f[4];
#pragma unroll
    for (int g = 0; g < 4; ++g) g_f[g] = ld1(gp + (size_t)idx * NG + g * NH);

    // B fragments: h[k] broadcast to all columns; k = c*32 + q*8 + j
    short8 bfr[4];
    const unsigned short* hrow = hpk[s & 1];
#pragma unroll
    for (int c = 0; c < 4; ++c) bfr[c] = *(const short8*)&hrow[c * 32 + q * 8];

    f32x4 acc[4];
#pragma unroll
    for (int g = 0; g < 4; ++g) {
      f32x4 z = {0.f, 0.f, 0.f, 0.f};
      acc[g] = z;
#pragma unroll
      for (int c = 0; c < 4; ++c)
        acc[g] = __builtin_amdgcn_mfma_f32_16x16x32_bf16(afr[g][c], bfr[c], acc[g], 0, 0, 0);
    }

    // select acc[g][r] (r = m&3) via 3 cndmasks per gate
    float pre[4];
#pragma unroll
    for (int g = 0; g < 4; ++g) {
      const float t0v = (r & 1) ? acc[g][1] : acc[g][0];
      const float t1v = (r & 1) ? acc[g][3] : acc[g][2];
      pre[g] = ((r & 2) ? t1v : t0v) + g_c[g];
    }
    const float ig = sigmoid_fast(pre[0]);
    const float fg = sigmoid_fast(pre[1]);
    const float gg = tanh_fast(pre[2]);
    const float og = sigmoid_fast(pre[3]);
    ccur = fmaf(fg, ccur, ig * gg);
    hcur = og * tanh_fast(ccur);
    if (m < 4) hpk[(s + 1) & 1][u] = f2bf(hcur);
    __syncthreads();

#pragma unroll
    for (int g = 0; g < 4; ++g) {
      g_c[g] = g_n[g];
      g_n[g] = g_f[g];
    }
  }

  if (!last) {
    if (m < 4) {
      hstate[(size_t)bc * NH + u] = hcur;
      cstate[(size_t)bc * NH + u] = ccur;
    }
  } else {
    if (m < 4) hf[u] = hcur;
    __syncthreads();
    if (tid < NC) {
      float acc = ld1(fcb + tid);
      const XT* wv = fcw + (size_t)tid * NH;
#pragma unroll
      for (int k = 0; k < NH; ++k) acc = fmaf(ld1(wv + k), hf[k], acc);
      st1(out + (size_t)b * NC + tid, acc);
    }
  }
}

// ---------------------------------------------------------------------------
template <typename XT, typename GXT>
static void run_variant(int want, const int* flag, void* const* d_in, XT* out,
                        GXT* gx, float* hstate, float* cstate, int NBc, int Tc,
                        hipStream_t stream) {
  const XT* X = (const XT*)d_in[0];
  const XT* Wih = (const XT*)d_in[1];
  const XT* Whh = (const XT*)d_in[2];
  const XT* bih = (const XT*)d_in[3];
  const XT* bhh = (const XT*)d_in[4];
  const XT* fcw = (const XT*)d_in[5];
  const XT* fcb = (const XT*)d_in[6];
  const int* lengths = (const int*)d_in[7];
  for (int bb = 0; bb < NB; bb += NBc) {
    for (int tb = 0; tb < NT; tb += Tc) {
      gx_gemm<XT, GXT><<<dim3((NBc * Tc) / 128), dim3(256), 0, stream>>>(
          flag, want, X, Wih, bih, bhh, lengths, gx, bb, tb, Tc);
      lstm_rec<XT, GXT><<<dim3(NBc), dim3(512), 0, stream>>>(
          flag, want, gx, Whh, fcw, fcb, lengths, out, hstate, cstate, bb, tb, Tc);
    }
  }
}

extern "C" void kernel_launch(void* const* d_in, const int* in_sizes, int n_in,
                              void* d_out, int out_size, void* d_ws, size_t ws_size,
                              hipStream_t stream) {
  int* flag = (int*)d_ws;
  detect_dtype<<<dim3(1), dim3(64), 0, stream>>>((const unsigned short*)d_in[0], flag);

  const size_t full_f32 = (size_t)NB * NT * NG * sizeof(float);
  const size_t full_bf16 = (size_t)NB * NT * NG * 2;
  const size_t base = 512;

  int NBc, Tc;
  char* gx_raw;
  float* hstate = (float*)((char*)d_ws + base);
  bool gx_is_f32;

  if (ws_size >= base + full_f32) {
    NBc = NB; Tc = NT; gx_is_f32 = true;
    gx_raw = (char*)d_ws + base;
  } else if (ws_size >= base + full_bf16) {
    NBc = NB; Tc = NT; gx_is_f32 = false;
    gx_raw = (char*)d_ws + base;
  } else {
    Tc = 128; gx_is_f32 = false;
    NBc = 1;
    for (int cand : {64, 16, 4}) {
      size_t need = base + (size_t)cand * NH * 2 * sizeof(float) + (size_t)cand * Tc * NG * 2;
      if (ws_size >= need) { NBc = cand; break; }
    }
    gx_raw = (char*)d_ws + base + (size_t)NBc * NH * 2 * sizeof(float);
  }
  float* cstate = hstate + (size_t)NBc * NH;

  if (gx_is_f32) {
    run_variant<unsigned short, float>(0, flag, d_in, (unsigned short*)d_out,
                                       (float*)gx_raw, hstate, cstate, NBc, Tc, stream);
    run_variant<float, float>(1, flag, d_in, (float*)d_out, (float*)gx_raw, hstate,
                              cstate, NBc, Tc, stream);
  } else {
    run_variant<unsigned short, unsigned short>(0, flag, d_in, (unsigned short*)d_out,
                                                (unsigned short*)gx_raw, hstate, cstate,
                                                NBc, Tc, stream);
    run_variant<float, unsigned short>(1, flag, d_in, (float*)d_out,
                                       (unsigned short*)gx_raw, hstate, cstate, NBc, Tc,
                                       stream);
  }
}